// Round 4
// baseline (262.531 us; speedup 1.0000x reference)
//
#include <hip/hip_runtime.h>
#include <hip/hip_bf16.h>
#include <stdint.h>

#define TB 2
#define TS 2048
#define TD 1024
#define TH 16
#define THS 64
#define TK 1024  // inner dim of both GEMMs

typedef __attribute__((ext_vector_type(8))) short short8;
typedef __attribute__((ext_vector_type(4))) short short4v;
typedef __attribute__((ext_vector_type(4))) float f32x4;
typedef __attribute__((ext_vector_type(16))) float f32x16;
typedef __attribute__((ext_vector_type(4))) unsigned int uint4v;

static __device__ __forceinline__ unsigned short f2bf(float f) {
  union { float f; unsigned u; } v; v.f = f;
  unsigned r = v.u + 0x7FFFu + ((v.u >> 16) & 1u);  // RTNE
  return (unsigned short)(r >> 16);
}

// pack two f32 -> (hi:bf16(b), lo:bf16(a))
static __device__ __forceinline__ unsigned cvtpk(float a, float b) {
  unsigned r;
  asm("v_cvt_pk_bf16_f32 %0, %1, %2" : "=v"(r) : "v"(a), "v"(b));
  return r;
}

// exchange: a.lanes[32:63] <-> b.lanes[0:31]
static __device__ __forceinline__ void swap32(unsigned& a, unsigned& b) {
  asm("v_permlane32_swap_b32 %0, %1" : "+v"(a), "+v"(b));
}

static __device__ __forceinline__ void async_copy16(const void* g, void* l) {
  __builtin_amdgcn_global_load_lds(
      (const __attribute__((address_space(1))) unsigned int*)g,
      (__attribute__((address_space(3))) unsigned int*)l, 16, 0, 0);
}

// ---------------- elementwise fp32 -> bf16 cast ----------------
__global__ __launch_bounds__(256) void k_cvt_bf16x4(const float* __restrict__ in,
                                                    ushort4* __restrict__ out, int n4) {
  int i = blockIdx.x * blockDim.x + threadIdx.x;
  if (i >= n4) return;
  float4 v = ((const float4*)in)[i];
  out[i] = make_ushort4(f2bf(v.x), f2bf(v.y), f2bf(v.z), f2bf(v.w));
}

// ---------------- fp32 [R][C] -> bf16 [C][R] transpose ----------------
__global__ __launch_bounds__(256) void k_transpose_bf(const float* __restrict__ in,
                                                      unsigned short* __restrict__ out,
                                                      int R, int C) {
  __shared__ float tile[32][33];
  const int tx = threadIdx.x & 31, ty = threadIdx.x >> 5;  // ty 0..7
  const int r0 = blockIdx.y * 32, c0 = blockIdx.x * 32;
#pragma unroll
  for (int i = 0; i < 32; i += 8)
    tile[ty + i][tx] = in[(size_t)(r0 + ty + i) * C + c0 + tx];
  __syncthreads();
#pragma unroll
  for (int i = 0; i < 32; i += 8)
    out[(size_t)(c0 + ty + i) * R + r0 + tx] = f2bf(tile[tx][ty + i]);
}

// ---------------- shared GEMM core: C[128x128] tile, K=1024, A[M][K] bf16, BT[N][K] bf16 ----------------
__device__ __forceinline__ void gemm_core_k1024(const unsigned short* __restrict__ A,
                                                const unsigned short* __restrict__ BT,
                                                int m0, int n0,
                                                unsigned short* sA, unsigned short* sB,
                                                f32x4 acc[4][4]) {
  const int tid = threadIdx.x;
  const int wave = tid >> 6, lane = tid & 63;
  const int wm = wave >> 1, wn = wave & 1;

  const unsigned short* gsrc = (wave < 2) ? A : BT;
  const int row0 = (wave < 2) ? m0 : n0;
  unsigned short* lbase = (wave < 2) ? sA : sB;
  const int cw = (wave & 1) * 4;
  const size_t gr = (size_t)(row0 + cw * 16 + (lane >> 2)) * TK + (lane & 3) * 8;

#pragma unroll
  for (int mi = 0; mi < 4; ++mi)
#pragma unroll
    for (int ni = 0; ni < 4; ++ni)
      acc[mi][ni] = (f32x4){0.f, 0.f, 0.f, 0.f};

  auto stage = [&](int buf, int kt) {
    const unsigned short* g = gsrc + gr + kt * 32;
    unsigned short* l = lbase + buf * 4096 + cw * 512;
#pragma unroll
    for (int c = 0; c < 4; ++c)
      async_copy16(g + (size_t)c * 16 * TK, l + c * 512);
  };

  stage(0, 0);
  __syncthreads();

  const int l15 = lane & 15, lk8 = (lane >> 4) * 8;
  const int aoff = (wm * 64 + l15) * 32 + lk8;
  const int boff = (wn * 64 + l15) * 32 + lk8;

  for (int kt = 0; kt < TK / 32; ++kt) {
    const int buf = kt & 1;
    if (kt + 1 < TK / 32) stage(buf ^ 1, kt + 1);
    short8 af[4], bfr[4];
#pragma unroll
    for (int i = 0; i < 4; ++i) {
      af[i] = *(const short8*)&sA[buf * 4096 + aoff + i * 16 * 32];
      bfr[i] = *(const short8*)&sB[buf * 4096 + boff + i * 16 * 32];
    }
#pragma unroll
    for (int mi = 0; mi < 4; ++mi)
#pragma unroll
      for (int ni = 0; ni < 4; ++ni)
        acc[mi][ni] = __builtin_amdgcn_mfma_f32_16x16x32_bf16(af[mi], bfr[ni], acc[mi][ni], 0, 0, 0);
    __syncthreads();
  }
}

// ---------------- GEMM1: qkv = xb @ waT^T + bias, scatter to Q/K [B,H,S,HS] and VT [B,H,HS,S] ----------------
__global__ __launch_bounds__(256) void k_gemm_qkv(const unsigned short* __restrict__ A,
                                                  const unsigned short* __restrict__ BT,
                                                  const float* __restrict__ bias,
                                                  unsigned short* __restrict__ Qo,
                                                  unsigned short* __restrict__ Ko,
                                                  unsigned short* __restrict__ VTo) {
  __shared__ unsigned short sA[2 * 4096];
  __shared__ unsigned short sB[2 * 4096];
  f32x4 acc[4][4];
  const int m0 = blockIdx.y * 128, n0 = blockIdx.x * 128;
  gemm_core_k1024(A, BT, m0, n0, sA, sB, acc);

  const int lane = threadIdx.x & 63, wave = threadIdx.x >> 6;
  const int wm = wave >> 1, wn = wave & 1;
  const int lr4 = (lane >> 4) * 4, l15 = lane & 15;
#pragma unroll
  for (int mi = 0; mi < 4; ++mi) {
    const int row = m0 + wm * 64 + mi * 16 + lr4;
#pragma unroll
    for (int ni = 0; ni < 4; ++ni) {
      const int col = n0 + wn * 64 + ni * 16 + l15;
      const float bi = bias[col];
      const int reg = col >> 10;      // 0:q 1:k 2:v
      const int d1 = col & 1023;
      const int h = d1 >> 6, d = d1 & 63;
#pragma unroll
      for (int j = 0; j < 4; ++j) {
        const int t = row + j;
        const int b = t >> 11, s = t & 2047;
        const unsigned short bv = f2bf(acc[mi][ni][j] + bi);
        if (reg == 0)
          Qo[(((size_t)b * TH + h) * TS + s) * THS + d] = bv;
        else if (reg == 1)
          Ko[(((size_t)b * TH + h) * TS + s) * THS + d] = bv;
        else
          VTo[(((size_t)b * TH + h) * THS + d) * TS + s] = bv;
      }
    }
  }
}

// ---------------- flash attention, causal, swapped-operand in-register softmax ----------------
// 4-wave blocks (R2 structure: best measured) + XCD-locality mapping (R3's proven FETCH win).
// Block lin: xcd = lin&7 owns 4 (b,h) pairs -> K/V L2-resident (2 MB / 4 MB per XCD).
// Within XCD: g = pair, jt zigzag over 16 qt-groups balances the causal triangle.
// Wave owns 32 q-rows; KVBLK=32; swapped QK^T (S^T = mfma(K,Q)) keeps softmax per-lane:
// tree-max (v_max3-fusible) + 1 shfl_xor(32); T13 defer-rescale; T5 setprio around MFMA.
__global__ __launch_bounds__(256) void k_attn(const unsigned short* __restrict__ Q,
                                              const unsigned short* __restrict__ K,
                                              const unsigned short* __restrict__ VT,
                                              unsigned short* __restrict__ attn) {
  __shared__ unsigned short sO[4][32 * 68];  // per-wave O transpose buffer, stride 68
  const int lane = threadIdx.x & 63, wave = threadIdx.x >> 6;
  const int l31 = lane & 31, h = lane >> 5;

  const int lin = blockIdx.x;                  // 512 blocks
  const int xcd = lin & 7, j = lin >> 3;       // j in [0,64)
  const int g = j >> 4, jt = j & 15;
  const int pair = xcd * 4 + g;                // 4 (b,h) pairs per XCD
  const int b = pair >> 4, hh = pair & 15;
  const int qt = (jt & 1) ? (jt >> 1) : 15 - (jt >> 1);  // zigzag: 15,0,14,1,...
  const int qrb = qt * 128 + wave * 32;

  const unsigned short* Qh = Q + (((size_t)b * TH + hh) * TS) * THS;
  const unsigned short* Kh = K + (((size_t)b * TH + hh) * TS) * THS;
  const unsigned short* Vh = VT + (((size_t)b * TH + hh) * THS) * TS;

  // Q B-frags: lane holds row (qrb + l31), d-chunk c*16 + h*8
  short8 qf[4];
#pragma unroll
  for (int c2 = 0; c2 < 4; ++c2)
    qf[c2] = *(const short8*)&Qh[(size_t)(qrb + l31) * THS + c2 * 16 + h * 8];

  f32x16 o0 = {}, o1 = {};
  float m_run = -1e30f, l_run = 0.f;
  const float cl2e = 0.125f * 1.44269504088896340736f;  // scale * log2(e)
  const float THR = 8.0f / cl2e;                        // defer-rescale threshold (raw score)

  const int nkt = (qrb >> 5) + 1;

  // K A-frags for tile 0
  short8 kf[4];
#pragma unroll
  for (int c2 = 0; c2 < 4; ++c2)
    kf[c2] = *(const short8*)&Kh[(size_t)l31 * THS + c2 * 16 + h * 8];

  for (int kt = 0; kt < nkt; ++kt) {
    const int kb = kt * 32;
    // V^T A-frags for current tile (consumed after softmax -> latency-tolerant)
    short8 vf[2][2];
#pragma unroll
    for (int t = 0; t < 2; ++t)
#pragma unroll
      for (int c2 = 0; c2 < 2; ++c2)
        vf[t][c2] = *(const short8*)&Vh[(size_t)(t * 32 + l31) * TS + kb + c2 * 16 + h * 8];

    // S^T[k][q] accumulate over d
    f32x16 s = {};
    __builtin_amdgcn_s_setprio(1);
#pragma unroll
    for (int c2 = 0; c2 < 4; ++c2)
      s = __builtin_amdgcn_mfma_f32_32x32x16_bf16(kf[c2], qf[c2], s, 0, 0, 0);
    __builtin_amdgcn_s_setprio(0);

    // prefetch next K tile (in-place WAR; loads issue after mfma reads)
    if (kt + 1 < nkt) {
#pragma unroll
      for (int c2 = 0; c2 < 4; ++c2)
        kf[c2] = *(const short8*)&Kh[(size_t)(kb + 32 + l31) * THS + c2 * 16 + h * 8];
    }

    // causal mask on the diagonal tile (kb == qrb): k-row (reg-mapped) <= q (lane-mapped)
    if (kt == nkt - 1) {
#pragma unroll
      for (int r = 0; r < 16; ++r)
        if ((r & 3) + 8 * (r >> 2) + 4 * h > l31) s[r] = -1e30f;
    }

    // online softmax, per-lane state for q = l31 (replicated in both halves).
    // tree reduction: 4-cycle-deep chains instead of 15-deep; max3-fusible nesting.
    const float ma = fmaxf(fmaxf(s[0], s[1]), fmaxf(s[2], s[3]));
    const float mb = fmaxf(fmaxf(s[4], s[5]), fmaxf(s[6], s[7]));
    const float mc = fmaxf(fmaxf(s[8], s[9]), fmaxf(s[10], s[11]));
    const float md = fmaxf(fmaxf(s[12], s[13]), fmaxf(s[14], s[15]));
    float tm = fmaxf(fmaxf(ma, mb), fmaxf(mc, md));
    tm = fmaxf(tm, __shfl_xor(tm, 32));

    float al;
    if (__all(tm <= m_run + THR)) {
      al = 1.0f;  // defer: keep old max, P bounded by exp2(8)
    } else {
      const float mn = fmaxf(m_run, tm);
      al = __builtin_amdgcn_exp2f((m_run - mn) * cl2e);
      m_run = mn;
      o0 *= al;
      o1 *= al;
    }
#pragma unroll
    for (int r = 0; r < 16; ++r)
      s[r] = __builtin_amdgcn_exp2f((s[r] - m_run) * cl2e);
    // sum tree
    const float sa = (s[0] + s[1]) + (s[2] + s[3]);
    const float sb2 = (s[4] + s[5]) + (s[6] + s[7]);
    const float sc = (s[8] + s[9]) + (s[10] + s[11]);
    const float sd = (s[12] + s[13]) + (s[14] + s[15]);
    float ts = (sa + sb2) + (sc + sd);
    ts += __shfl_xor(ts, 32);
    l_run = l_run * al + ts;

    // P^T B-frags: pack pairs to bf16, pairwise permlane32_swap -> frag words in order
    unsigned B0 = cvtpk(s[0], s[1]), B1 = cvtpk(s[2], s[3]);
    unsigned B2 = cvtpk(s[4], s[5]), B3 = cvtpk(s[6], s[7]);
    swap32(B0, B2);
    swap32(B1, B3);
    unsigned B4 = cvtpk(s[8], s[9]), B5 = cvtpk(s[10], s[11]);
    unsigned B6 = cvtpk(s[12], s[13]), B7 = cvtpk(s[14], s[15]);
    swap32(B4, B6);
    swap32(B5, B7);
    union U { uint4v u; short8 s8; } u0, u1;
    u0.u = (uint4v){B0, B1, B2, B3};
    u1.u = (uint4v){B4, B5, B6, B7};

    __builtin_amdgcn_s_setprio(1);
    o0 = __builtin_amdgcn_mfma_f32_32x32x16_bf16(vf[0][0], u0.s8, o0, 0, 0, 0);
    o0 = __builtin_amdgcn_mfma_f32_32x32x16_bf16(vf[0][1], u1.s8, o0, 0, 0, 0);
    o1 = __builtin_amdgcn_mfma_f32_32x32x16_bf16(vf[1][0], u0.s8, o1, 0, 0, 0);
    o1 = __builtin_amdgcn_mfma_f32_32x32x16_bf16(vf[1][1], u1.s8, o1, 0, 0, 0);
    __builtin_amdgcn_s_setprio(0);
  }

  // epilogue: O^T -> LDS (wave-private, no barrier needed) -> coalesced global store
  const float inv = 1.0f / l_run;
  unsigned* so32 = (unsigned*)&sO[wave][0];
#pragma unroll
  for (int j2 = 0; j2 < 8; ++j2) {
    const int d0 = ((2 * j2) & 3) + 8 * (j2 >> 1) + 4 * h;  // even d of the pair
    so32[l31 * 34 + (d0 >> 1)] = cvtpk(o0[2 * j2] * inv, o0[2 * j2 + 1] * inv);
    so32[l31 * 34 + ((32 + d0) >> 1)] = cvtpk(o1[2 * j2] * inv, o1[2 * j2 + 1] * inv);
  }
#pragma unroll
  for (int p2 = 0; p2 < 4; ++p2) {
    const int rp = p2 * 8 + (lane >> 3);
    const int co = (lane & 7) * 8;
    short4v va = *(const short4v*)&sO[wave][rp * 68 + co];
    short4v vb = *(const short4v*)&sO[wave][rp * 68 + co + 4];
    unsigned short* gp = &attn[(size_t)(b * TS + qrb + rp) * TD + hh * THS + co];
    *(short4v*)gp = va;
    *(short4v*)(gp + 4) = vb;
  }
}

// ---------------- GEMM2: out = attn @ wpT^T + bias (fp32 out) ----------------
__global__ __launch_bounds__(256) void k_gemm_proj(const unsigned short* __restrict__ A,
                                                   const unsigned short* __restrict__ BT,
                                                   const float* __restrict__ bias,
                                                   float* __restrict__ out) {
  __shared__ unsigned short sA[2 * 4096];
  __shared__ unsigned short sB[2 * 4096];
  f32x4 acc[4][4];
  const int m0 = blockIdx.y * 128, n0 = blockIdx.x * 128;
  gemm_core_k1024(A, BT, m0, n0, sA, sB, acc);

  const int lane = threadIdx.x & 63, wave = threadIdx.x >> 6;
  const int wm = wave >> 1, wn = wave & 1;
  const int lr4 = (lane >> 4) * 4, l15 = lane & 15;
#pragma unroll
  for (int mi = 0; mi < 4; ++mi) {
    const int row = m0 + wm * 64 + mi * 16 + lr4;
#pragma unroll
    for (int ni = 0; ni < 4; ++ni) {
      const int col = n0 + wn * 64 + ni * 16 + l15;
      const float bi = bias[col];
#pragma unroll
      for (int j = 0; j < 4; ++j)
        out[(size_t)(row + j) * TD + col] = acc[mi][ni][j] + bi;
    }
  }
}

extern "C" void kernel_launch(void* const* d_in, const int* in_sizes, int n_in,
                              void* d_out, int out_size, void* d_ws, size_t ws_size,
                              hipStream_t stream) {
  const float* x = (const float*)d_in[0];
  const float* c_attn_w = (const float*)d_in[1];
  const float* c_attn_b = (const float*)d_in[2];
  const float* c_proj_w = (const float*)d_in[3];
  const float* c_proj_b = (const float*)d_in[4];
  float* out = (float*)d_out;

  const size_t SZ_XB = (size_t)4096 * 1024 * 2;
  const size_t SZ_WAT = (size_t)3072 * 1024 * 2;
  const size_t SZ_WPT = (size_t)1024 * 1024 * 2;
  const size_t SZ_HEAD = (size_t)TB * TH * TS * THS * 2;
  const size_t SZ_ATT = (size_t)4096 * 1024 * 2;
  if (ws_size < SZ_XB + SZ_WAT + SZ_WPT + 3 * SZ_HEAD + SZ_ATT) return;

  char* ws = (char*)d_ws;
  unsigned short* xb = (unsigned short*)ws;   ws += SZ_XB;
  unsigned short* waT = (unsigned short*)ws;  ws += SZ_WAT;
  unsigned short* wpT = (unsigned short*)ws;  ws += SZ_WPT;
  unsigned short* Qb = (unsigned short*)ws;   ws += SZ_HEAD;
  unsigned short* Kb = (unsigned short*)ws;   ws += SZ_HEAD;
  unsigned short* VTb = (unsigned short*)ws;  ws += SZ_HEAD;
  unsigned short* attn = (unsigned short*)ws; ws += SZ_ATT;

  k_cvt_bf16x4<<<4096, 256, 0, stream>>>(x, (ushort4*)xb, 4096 * 1024 / 4);
  k_transpose_bf<<<dim3(3072 / 32, 1024 / 32), 256, 0, stream>>>(c_attn_w, waT, 1024, 3072);
  k_transpose_bf<<<dim3(1024 / 32, 1024 / 32), 256, 0, stream>>>(c_proj_w, wpT, 1024, 1024);
  k_gemm_qkv<<<dim3(3072 / 128, 4096 / 128), 256, 0, stream>>>(xb, waT, c_attn_b, Qb, Kb, VTb);
  k_attn<<<dim3(512), 256, 0, stream>>>(Qb, Kb, VTb, attn);
  k_gemm_proj<<<dim3(1024 / 128, 4096 / 128), 256, 0, stream>>>(attn, wpT, c_proj_b, out);
}

// Round 5
// 225.223 us; speedup vs baseline: 1.1657x; 1.1657x over previous
//
#include <hip/hip_runtime.h>
#include <hip/hip_bf16.h>
#include <stdint.h>

#define TB 2
#define TS 2048
#define TD 1024
#define TH 16
#define THS 64
#define TK 1024  // inner dim of both GEMMs

typedef __attribute__((ext_vector_type(8))) short short8;
typedef __attribute__((ext_vector_type(4))) short short4v;
typedef __attribute__((ext_vector_type(4))) float f32x4;
typedef __attribute__((ext_vector_type(16))) float f32x16;
typedef __attribute__((ext_vector_type(4))) unsigned int uint4v;

static __device__ __forceinline__ unsigned short f2bf(float f) {
  union { float f; unsigned u; } v; v.f = f;
  unsigned r = v.u + 0x7FFFu + ((v.u >> 16) & 1u);  // RTNE
  return (unsigned short)(r >> 16);
}

// pack two f32 -> (hi:bf16(b), lo:bf16(a))
static __device__ __forceinline__ unsigned cvtpk(float a, float b) {
  unsigned r;
  asm("v_cvt_pk_bf16_f32 %0, %1, %2" : "=v"(r) : "v"(a), "v"(b));
  return r;
}

// exchange: a.lanes[32:63] <-> b.lanes[0:31]
static __device__ __forceinline__ void swap32(unsigned& a, unsigned& b) {
  asm("v_permlane32_swap_b32 %0, %1" : "+v"(a), "+v"(b));
}

static __device__ __forceinline__ void async_copy16(const void* g, void* l) {
  __builtin_amdgcn_global_load_lds(
      (const __attribute__((address_space(1))) unsigned int*)g,
      (__attribute__((address_space(3))) unsigned int*)l, 16, 0, 0);
}

// ---------------- elementwise fp32 -> bf16 cast ----------------
__global__ __launch_bounds__(256) void k_cvt_bf16x4(const float* __restrict__ in,
                                                    ushort4* __restrict__ out, int n4) {
  int i = blockIdx.x * blockDim.x + threadIdx.x;
  if (i >= n4) return;
  float4 v = ((const float4*)in)[i];
  out[i] = make_ushort4(f2bf(v.x), f2bf(v.y), f2bf(v.z), f2bf(v.w));
}

// ---------------- fp32 [R][C] -> bf16 [C][R] transpose ----------------
__global__ __launch_bounds__(256) void k_transpose_bf(const float* __restrict__ in,
                                                      unsigned short* __restrict__ out,
                                                      int R, int C) {
  __shared__ float tile[32][33];
  const int tx = threadIdx.x & 31, ty = threadIdx.x >> 5;  // ty 0..7
  const int r0 = blockIdx.y * 32, c0 = blockIdx.x * 32;
#pragma unroll
  for (int i = 0; i < 32; i += 8)
    tile[ty + i][tx] = in[(size_t)(r0 + ty + i) * C + c0 + tx];
  __syncthreads();
#pragma unroll
  for (int i = 0; i < 32; i += 8)
    out[(size_t)(c0 + ty + i) * R + r0 + tx] = f2bf(tile[tx][ty + i]);
}

// ---------------- shared GEMM core: C[128x128] tile, K=1024, A[M][K] bf16, BT[N][K] bf16 ----------------
__device__ __forceinline__ void gemm_core_k1024(const unsigned short* __restrict__ A,
                                                const unsigned short* __restrict__ BT,
                                                int m0, int n0,
                                                unsigned short* sA, unsigned short* sB,
                                                f32x4 acc[4][4]) {
  const int tid = threadIdx.x;
  const int wave = tid >> 6, lane = tid & 63;
  const int wm = wave >> 1, wn = wave & 1;

  const unsigned short* gsrc = (wave < 2) ? A : BT;
  const int row0 = (wave < 2) ? m0 : n0;
  unsigned short* lbase = (wave < 2) ? sA : sB;
  const int cw = (wave & 1) * 4;
  const size_t gr = (size_t)(row0 + cw * 16 + (lane >> 2)) * TK + (lane & 3) * 8;

#pragma unroll
  for (int mi = 0; mi < 4; ++mi)
#pragma unroll
    for (int ni = 0; ni < 4; ++ni)
      acc[mi][ni] = (f32x4){0.f, 0.f, 0.f, 0.f};

  auto stage = [&](int buf, int kt) {
    const unsigned short* g = gsrc + gr + kt * 32;
    unsigned short* l = lbase + buf * 4096 + cw * 512;
#pragma unroll
    for (int c = 0; c < 4; ++c)
      async_copy16(g + (size_t)c * 16 * TK, l + c * 512);
  };

  stage(0, 0);
  __syncthreads();

  const int l15 = lane & 15, lk8 = (lane >> 4) * 8;
  const int aoff = (wm * 64 + l15) * 32 + lk8;
  const int boff = (wn * 64 + l15) * 32 + lk8;

  for (int kt = 0; kt < TK / 32; ++kt) {
    const int buf = kt & 1;
    if (kt + 1 < TK / 32) stage(buf ^ 1, kt + 1);
    short8 af[4], bfr[4];
#pragma unroll
    for (int i = 0; i < 4; ++i) {
      af[i] = *(const short8*)&sA[buf * 4096 + aoff + i * 16 * 32];
      bfr[i] = *(const short8*)&sB[buf * 4096 + boff + i * 16 * 32];
    }
#pragma unroll
    for (int mi = 0; mi < 4; ++mi)
#pragma unroll
      for (int ni = 0; ni < 4; ++ni)
        acc[mi][ni] = __builtin_amdgcn_mfma_f32_16x16x32_bf16(af[mi], bfr[ni], acc[mi][ni], 0, 0, 0);
    __syncthreads();
  }
}

// ---------------- GEMM1: qkv = xb @ waT^T + bias, scatter to Q/K [B,H,S,HS] and VT [B,H,HS,S] ----------------
__global__ __launch_bounds__(256) void k_gemm_qkv(const unsigned short* __restrict__ A,
                                                  const unsigned short* __restrict__ BT,
                                                  const float* __restrict__ bias,
                                                  unsigned short* __restrict__ Qo,
                                                  unsigned short* __restrict__ Ko,
                                                  unsigned short* __restrict__ VTo) {
  __shared__ unsigned short sA[2 * 4096];
  __shared__ unsigned short sB[2 * 4096];
  f32x4 acc[4][4];
  const int m0 = blockIdx.y * 128, n0 = blockIdx.x * 128;
  gemm_core_k1024(A, BT, m0, n0, sA, sB, acc);

  const int lane = threadIdx.x & 63, wave = threadIdx.x >> 6;
  const int wm = wave >> 1, wn = wave & 1;
  const int lr4 = (lane >> 4) * 4, l15 = lane & 15;
#pragma unroll
  for (int mi = 0; mi < 4; ++mi) {
    const int row = m0 + wm * 64 + mi * 16 + lr4;
#pragma unroll
    for (int ni = 0; ni < 4; ++ni) {
      const int col = n0 + wn * 64 + ni * 16 + l15;
      const float bi = bias[col];
      const int reg = col >> 10;      // 0:q 1:k 2:v
      const int d1 = col & 1023;
      const int h = d1 >> 6, d = d1 & 63;
#pragma unroll
      for (int j = 0; j < 4; ++j) {
        const int t = row + j;
        const int b = t >> 11, s = t & 2047;
        const unsigned short bv = f2bf(acc[mi][ni][j] + bi);
        if (reg == 0)
          Qo[(((size_t)b * TH + h) * TS + s) * THS + d] = bv;
        else if (reg == 1)
          Ko[(((size_t)b * TH + h) * TS + s) * THS + d] = bv;
        else
          VTo[(((size_t)b * TH + h) * THS + d) * TS + s] = bv;
      }
    }
  }
}

// ---------------- flash attention, causal, swapped-operand in-register softmax ----------------
// EXACT R2 structure (grid (16,16,2), b-complement, 4-wave blocks, KVBLK=32, per-wave V
// prefetch) + ONE change: K tiles staged once per block into LDS via global_load_lds,
// double-buffered, XOR-swizzled (byte ^= (row&7)<<4) via pre-swizzled global source +
// swizzled ds_read (both-sides rule). All waves iterate the block-uniform kv range
// (4qt+4 tiles); trailing fully-masked tiles contribute 0 through the causal mask.
__global__ __launch_bounds__(256) void k_attn(const unsigned short* __restrict__ Q,
                                              const unsigned short* __restrict__ K,
                                              const unsigned short* __restrict__ VT,
                                              unsigned short* __restrict__ attn) {
  __shared__ unsigned short sK[2 * 2048];    // K dbuf: 2 x 32 rows x 64 elems (4 KB each)
  __shared__ unsigned short sO[4][32 * 68];  // per-wave O transpose buffer, stride 68
  const int tid = threadIdx.x;
  const int lane = tid & 63, wave = tid >> 6;
  const int l31 = lane & 31, h = lane >> 5;
  int qt = blockIdx.x;
  const int hh = blockIdx.y, b = blockIdx.z;
  if (b) qt = 15 - qt;  // complement pairing balances the causal triangle across CUs
  const int qrb = qt * 128 + wave * 32;

  const unsigned short* Qh = Q + (((size_t)b * TH + hh) * TS) * THS;
  const unsigned short* Kh = K + (((size_t)b * TH + hh) * TS) * THS;
  const unsigned short* Vh = VT + (((size_t)b * TH + hh) * THS) * TS;

  // Q B-frags: lane holds row (qrb + l31), d-chunk c*16 + h*8
  short8 qf[4];
#pragma unroll
  for (int c2 = 0; c2 < 4; ++c2)
    qf[c2] = *(const short8*)&Qh[(size_t)(qrb + l31) * THS + c2 * 16 + h * 8];

  f32x16 o0 = {}, o1 = {};
  float m_run = -1e30f, l_run = 0.f;
  const float cl2e = 0.125f * 1.44269504088896340736f;  // scale * log2(e)
  const float THR = 8.0f / cl2e;                        // defer-rescale threshold (raw score)

  const int nkt = 4 * qt + 4;  // block-uniform kv-tile count

  // stage K tile kt2 into LDS buf. 256 threads x 16B = 4 KB.
  // XOR swizzle: physical 16B-block bb holds global block (bb ^ (row&7)).
  const int srow = tid >> 3, sbb = tid & 7;
  const int ssrc = srow * THS + 8 * (sbb ^ (srow & 7));  // pre-swizzled global offset (elems)
  auto stageK = [&](int buf, int kt2) {
    async_copy16(Kh + (size_t)kt2 * 32 * THS + ssrc, sK + buf * 2048 + tid * 8);
  };

  stageK(0, 0);
  __syncthreads();  // drains vmcnt -> tile 0 visible to all waves

  // swizzled kf read offsets: logical (row=l31, block 2*c2+h) -> physical block ^(l31&7)
  int koff[4];
#pragma unroll
  for (int c2 = 0; c2 < 4; ++c2)
    koff[c2] = l31 * 64 + 8 * (((c2 << 1) | h) ^ (l31 & 7));

  for (int kt = 0; kt < nkt; ++kt) {
    const int kb = kt * 32;
    const int buf = kt & 1;
    // V^T A-frags for current tile (global, per-wave; consumed after softmax)
    short8 vf[2][2];
#pragma unroll
    for (int t = 0; t < 2; ++t)
#pragma unroll
      for (int c2 = 0; c2 < 2; ++c2)
        vf[t][c2] = *(const short8*)&Vh[(size_t)(t * 32 + l31) * TS + kb + c2 * 16 + h * 8];

    // K A-frags from LDS (swizzled, conflict-free)
    const unsigned short* kl = sK + buf * 2048;
    short8 kf[4];
#pragma unroll
    for (int c2 = 0; c2 < 4; ++c2)
      kf[c2] = *(const short8*)&kl[koff[c2]];

    // stage next K tile into the other buffer (async; prev tile's reads done at last barrier)
    if (kt + 1 < nkt) stageK(buf ^ 1, kt + 1);

    // S^T[k][q] accumulate over d
    f32x16 s = {};
#pragma unroll
    for (int c2 = 0; c2 < 4; ++c2)
      s = __builtin_amdgcn_mfma_f32_32x32x16_bf16(kf[c2], qf[c2], s, 0, 0, 0);

    // causal mask: k = kb + rowmap(r,h), q = qrb + l31; also fully masks tiles kb > qrb
    const int dlt = kb - qrb;
    if (dlt >= 0) {
#pragma unroll
      for (int r = 0; r < 16; ++r)
        if (dlt + (r & 3) + 8 * (r >> 2) + 4 * h > l31) s[r] = -1e30f;
    }

    // online softmax, per-lane state for q = l31 (replicated in both halves); tree reductions
    const float ma = fmaxf(fmaxf(s[0], s[1]), fmaxf(s[2], s[3]));
    const float mb = fmaxf(fmaxf(s[4], s[5]), fmaxf(s[6], s[7]));
    const float mc = fmaxf(fmaxf(s[8], s[9]), fmaxf(s[10], s[11]));
    const float md = fmaxf(fmaxf(s[12], s[13]), fmaxf(s[14], s[15]));
    float tm = fmaxf(fmaxf(ma, mb), fmaxf(mc, md));
    tm = fmaxf(tm, __shfl_xor(tm, 32));

    float al;
    if (__all(tm <= m_run + THR)) {
      al = 1.0f;  // defer: keep old max, P bounded by exp2(8)
    } else {
      const float mn = fmaxf(m_run, tm);
      al = __builtin_amdgcn_exp2f((m_run - mn) * cl2e);
      m_run = mn;
      o0 *= al;
      o1 *= al;
    }
#pragma unroll
    for (int r = 0; r < 16; ++r)
      s[r] = __builtin_amdgcn_exp2f((s[r] - m_run) * cl2e);
    const float sa = (s[0] + s[1]) + (s[2] + s[3]);
    const float sb2 = (s[4] + s[5]) + (s[6] + s[7]);
    const float sc = (s[8] + s[9]) + (s[10] + s[11]);
    const float sd = (s[12] + s[13]) + (s[14] + s[15]);
    float ts = (sa + sb2) + (sc + sd);
    ts += __shfl_xor(ts, 32);
    l_run = l_run * al + ts;

    // P^T B-frags: pack pairs to bf16, pairwise permlane32_swap -> frag words in order
    unsigned B0 = cvtpk(s[0], s[1]), B1 = cvtpk(s[2], s[3]);
    unsigned B2 = cvtpk(s[4], s[5]), B3 = cvtpk(s[6], s[7]);
    swap32(B0, B2);
    swap32(B1, B3);
    unsigned B4 = cvtpk(s[8], s[9]), B5 = cvtpk(s[10], s[11]);
    unsigned B6 = cvtpk(s[12], s[13]), B7 = cvtpk(s[14], s[15]);
    swap32(B4, B6);
    swap32(B5, B7);
    union U { uint4v u; short8 s8; } u0, u1;
    u0.u = (uint4v){B0, B1, B2, B3};
    u1.u = (uint4v){B4, B5, B6, B7};

    o0 = __builtin_amdgcn_mfma_f32_32x32x16_bf16(vf[0][0], u0.s8, o0, 0, 0, 0);
    o0 = __builtin_amdgcn_mfma_f32_32x32x16_bf16(vf[0][1], u1.s8, o0, 0, 0, 0);
    o1 = __builtin_amdgcn_mfma_f32_32x32x16_bf16(vf[1][0], u0.s8, o1, 0, 0, 0);
    o1 = __builtin_amdgcn_mfma_f32_32x32x16_bf16(vf[1][1], u1.s8, o1, 0, 0, 0);

    __syncthreads();  // drains stage vmcnt + protects buffer swap
  }

  // epilogue: O^T -> LDS (wave-private, no barrier needed) -> coalesced global store
  const float inv = 1.0f / l_run;
  unsigned* so32 = (unsigned*)&sO[wave][0];
#pragma unroll
  for (int j2 = 0; j2 < 8; ++j2) {
    const int d0 = ((2 * j2) & 3) + 8 * (j2 >> 1) + 4 * h;  // even d of the pair
    so32[l31 * 34 + (d0 >> 1)] = cvtpk(o0[2 * j2] * inv, o0[2 * j2 + 1] * inv);
    so32[l31 * 34 + ((32 + d0) >> 1)] = cvtpk(o1[2 * j2] * inv, o1[2 * j2 + 1] * inv);
  }
#pragma unroll
  for (int p2 = 0; p2 < 4; ++p2) {
    const int rp = p2 * 8 + (lane >> 3);
    const int co = (lane & 7) * 8;
    short4v va = *(const short4v*)&sO[wave][rp * 68 + co];
    short4v vb = *(const short4v*)&sO[wave][rp * 68 + co + 4];
    unsigned short* gp = &attn[(size_t)(b * TS + qrb + rp) * TD + hh * THS + co];
    *(short4v*)gp = va;
    *(short4v*)(gp + 4) = vb;
  }
}

// ---------------- GEMM2: out = attn @ wpT^T + bias (fp32 out) ----------------
__global__ __launch_bounds__(256) void k_gemm_proj(const unsigned short* __restrict__ A,
                                                   const unsigned short* __restrict__ BT,
                                                   const float* __restrict__ bias,
                                                   float* __restrict__ out) {
  __shared__ unsigned short sA[2 * 4096];
  __shared__ unsigned short sB[2 * 4096];
  f32x4 acc[4][4];
  const int m0 = blockIdx.y * 128, n0 = blockIdx.x * 128;
  gemm_core_k1024(A, BT, m0, n0, sA, sB, acc);

  const int lane = threadIdx.x & 63, wave = threadIdx.x >> 6;
  const int wm = wave >> 1, wn = wave & 1;
  const int lr4 = (lane >> 4) * 4, l15 = lane & 15;
#pragma unroll
  for (int mi = 0; mi < 4; ++mi) {
    const int row = m0 + wm * 64 + mi * 16 + lr4;
#pragma unroll
    for (int ni = 0; ni < 4; ++ni) {
      const int col = n0 + wn * 64 + ni * 16 + l15;
      const float bi = bias[col];
#pragma unroll
      for (int j = 0; j < 4; ++j)
        out[(size_t)(row + j) * TD + col] = acc[mi][ni][j] + bi;
    }
  }
}

extern "C" void kernel_launch(void* const* d_in, const int* in_sizes, int n_in,
                              void* d_out, int out_size, void* d_ws, size_t ws_size,
                              hipStream_t stream) {
  const float* x = (const float*)d_in[0];
  const float* c_attn_w = (const float*)d_in[1];
  const float* c_attn_b = (const float*)d_in[2];
  const float* c_proj_w = (const float*)d_in[3];
  const float* c_proj_b = (const float*)d_in[4];
  float* out = (float*)d_out;

  const size_t SZ_XB = (size_t)4096 * 1024 * 2;
  const size_t SZ_WAT = (size_t)3072 * 1024 * 2;
  const size_t SZ_WPT = (size_t)1024 * 1024 * 2;
  const size_t SZ_HEAD = (size_t)TB * TH * TS * THS * 2;
  const size_t SZ_ATT = (size_t)4096 * 1024 * 2;
  if (ws_size < SZ_XB + SZ_WAT + SZ_WPT + 3 * SZ_HEAD + SZ_ATT) return;

  char* ws = (char*)d_ws;
  unsigned short* xb = (unsigned short*)ws;   ws += SZ_XB;
  unsigned short* waT = (unsigned short*)ws;  ws += SZ_WAT;
  unsigned short* wpT = (unsigned short*)ws;  ws += SZ_WPT;
  unsigned short* Qb = (unsigned short*)ws;   ws += SZ_HEAD;
  unsigned short* Kb = (unsigned short*)ws;   ws += SZ_HEAD;
  unsigned short* VTb = (unsigned short*)ws;  ws += SZ_HEAD;
  unsigned short* attn = (unsigned short*)ws; ws += SZ_ATT;

  k_cvt_bf16x4<<<4096, 256, 0, stream>>>(x, (ushort4*)xb, 4096 * 1024 / 4);
  k_transpose_bf<<<dim3(3072 / 32, 1024 / 32), 256, 0, stream>>>(c_attn_w, waT, 1024, 3072);
  k_transpose_bf<<<dim3(1024 / 32, 1024 / 32), 256, 0, stream>>>(c_proj_w, wpT, 1024, 1024);
  k_gemm_qkv<<<dim3(3072 / 128, 4096 / 128), 256, 0, stream>>>(xb, waT, c_attn_b, Qb, Kb, VTb);
  k_attn<<<dim3(16, TH, TB), 256, 0, stream>>>(Qb, Kb, VTb, attn);
  k_gemm_proj<<<dim3(1024 / 128, 4096 / 128), 256, 0, stream>>>(attn, wpT, c_proj_b, out);
}

// Round 6
// 209.175 us; speedup vs baseline: 1.2551x; 1.0767x over previous
//
#include <hip/hip_runtime.h>
#include <hip/hip_bf16.h>
#include <stdint.h>

#define TB 2
#define TS 2048
#define TD 1024
#define TH 16
#define THS 64
#define TK 1024  // inner dim of both GEMMs

typedef __attribute__((ext_vector_type(8))) short short8;
typedef __attribute__((ext_vector_type(4))) short short4v;
typedef __attribute__((ext_vector_type(4))) float f32x4;
typedef __attribute__((ext_vector_type(16))) float f32x16;
typedef __attribute__((ext_vector_type(4))) unsigned int uint4v;

static __device__ __forceinline__ unsigned short f2bf(float f) {
  union { float f; unsigned u; } v; v.f = f;
  unsigned r = v.u + 0x7FFFu + ((v.u >> 16) & 1u);  // RTNE
  return (unsigned short)(r >> 16);
}

// pack two f32 -> (hi:bf16(b), lo:bf16(a))
static __device__ __forceinline__ unsigned cvtpk(float a, float b) {
  unsigned r;
  asm("v_cvt_pk_bf16_f32 %0, %1, %2" : "=v"(r) : "v"(a), "v"(b));
  return r;
}

// exchange: a.lanes[32:63] <-> b.lanes[0:31]
static __device__ __forceinline__ void swap32(unsigned& a, unsigned& b) {
  asm("v_permlane32_swap_b32 %0, %1" : "+v"(a), "+v"(b));
}

static __device__ __forceinline__ void async_copy16(const void* g, void* l) {
  __builtin_amdgcn_global_load_lds(
      (const __attribute__((address_space(1))) unsigned int*)g,
      (__attribute__((address_space(3))) unsigned int*)l, 16, 0, 0);
}

// ---------------- elementwise fp32 -> bf16 cast ----------------
__global__ __launch_bounds__(256) void k_cvt_bf16x4(const float* __restrict__ in,
                                                    ushort4* __restrict__ out, int n4) {
  int i = blockIdx.x * blockDim.x + threadIdx.x;
  if (i >= n4) return;
  float4 v = ((const float4*)in)[i];
  out[i] = make_ushort4(f2bf(v.x), f2bf(v.y), f2bf(v.z), f2bf(v.w));
}

// ---------------- fp32 [R][C] -> bf16 [C][R] transpose ----------------
__global__ __launch_bounds__(256) void k_transpose_bf(const float* __restrict__ in,
                                                      unsigned short* __restrict__ out,
                                                      int R, int C) {
  __shared__ float tile[32][33];
  const int tx = threadIdx.x & 31, ty = threadIdx.x >> 5;  // ty 0..7
  const int r0 = blockIdx.y * 32, c0 = blockIdx.x * 32;
#pragma unroll
  for (int i = 0; i < 32; i += 8)
    tile[ty + i][tx] = in[(size_t)(r0 + ty + i) * C + c0 + tx];
  __syncthreads();
#pragma unroll
  for (int i = 0; i < 32; i += 8)
    out[(size_t)(c0 + ty + i) * R + r0 + tx] = f2bf(tile[tx][ty + i]);
}

// ---------------- shared GEMM core: C[128x128] tile, K=1024, A[M][K] bf16, BT[N][K] bf16 ----------------
__device__ __forceinline__ void gemm_core_k1024(const unsigned short* __restrict__ A,
                                                const unsigned short* __restrict__ BT,
                                                int m0, int n0,
                                                unsigned short* sA, unsigned short* sB,
                                                f32x4 acc[4][4]) {
  const int tid = threadIdx.x;
  const int wave = tid >> 6, lane = tid & 63;
  const int wm = wave >> 1, wn = wave & 1;

  const unsigned short* gsrc = (wave < 2) ? A : BT;
  const int row0 = (wave < 2) ? m0 : n0;
  unsigned short* lbase = (wave < 2) ? sA : sB;
  const int cw = (wave & 1) * 4;
  const size_t gr = (size_t)(row0 + cw * 16 + (lane >> 2)) * TK + (lane & 3) * 8;

#pragma unroll
  for (int mi = 0; mi < 4; ++mi)
#pragma unroll
    for (int ni = 0; ni < 4; ++ni)
      acc[mi][ni] = (f32x4){0.f, 0.f, 0.f, 0.f};

  auto stage = [&](int buf, int kt) {
    const unsigned short* g = gsrc + gr + kt * 32;
    unsigned short* l = lbase + buf * 4096 + cw * 512;
#pragma unroll
    for (int c = 0; c < 4; ++c)
      async_copy16(g + (size_t)c * 16 * TK, l + c * 512);
  };

  stage(0, 0);
  __syncthreads();

  const int l15 = lane & 15, lk8 = (lane >> 4) * 8;
  const int aoff = (wm * 64 + l15) * 32 + lk8;
  const int boff = (wn * 64 + l15) * 32 + lk8;

  for (int kt = 0; kt < TK / 32; ++kt) {
    const int buf = kt & 1;
    if (kt + 1 < TK / 32) stage(buf ^ 1, kt + 1);
    short8 af[4], bfr[4];
#pragma unroll
    for (int i = 0; i < 4; ++i) {
      af[i] = *(const short8*)&sA[buf * 4096 + aoff + i * 16 * 32];
      bfr[i] = *(const short8*)&sB[buf * 4096 + boff + i * 16 * 32];
    }
#pragma unroll
    for (int mi = 0; mi < 4; ++mi)
#pragma unroll
      for (int ni = 0; ni < 4; ++ni)
        acc[mi][ni] = __builtin_amdgcn_mfma_f32_16x16x32_bf16(af[mi], bfr[ni], acc[mi][ni], 0, 0, 0);
    __syncthreads();
  }
}

// ---------------- GEMM1: qkv = xb @ waT^T + bias -> Q/K [B,H,S,HS] and VT [B,H,HS,S] ----------------
// Epilogue: per-wave 64x64 LDS transpose (stride-68, R2-proven pattern) -> 16B coalesced
// stores. Each 64-col block is exactly one head and one of {Q,K,V}; V stored [c][r] so its
// transposed (VT) rows come out contiguous. LDS reuses the staging buffers (safe: the
// K-loop's final __syncthreads has retired all sA/sB reads). No extra barriers.
__global__ __launch_bounds__(256) void k_gemm_qkv(const unsigned short* __restrict__ A,
                                                  const unsigned short* __restrict__ BT,
                                                  const float* __restrict__ bias,
                                                  unsigned short* __restrict__ Qo,
                                                  unsigned short* __restrict__ Ko,
                                                  unsigned short* __restrict__ VTo) {
  __shared__ unsigned short smem[4 * 64 * 68];  // 34816 B; front 32 KB doubles as sA/sB
  unsigned short* sA = smem;
  unsigned short* sB = smem + 8192;
  f32x4 acc[4][4];
  const int m0 = blockIdx.y * 128, n0 = blockIdx.x * 128;
  gemm_core_k1024(A, BT, m0, n0, sA, sB, acc);

  const int lane = threadIdx.x & 63, wave = threadIdx.x >> 6;
  const int wm = wave >> 1, wn = wave & 1;
  const int lr4 = (lane >> 4) * 4, l15 = lane & 15;

  const int col0 = n0 + wn * 64;   // 64-aligned -> one head, one region (uniform per wave)
  const int reg = col0 >> 10;      // 0:q 1:k 2:v
  const int h0 = (col0 & 1023) >> 6;
  const bool isV = (reg == 2);
  const int t0 = m0 + wm * 64;     // first row of this wave's subtile
  const int b = t0 >> 11;          // constant within subtile (128 | 2048)
  const int s0 = t0 & 2047;

  unsigned short* tw = smem + wave * (64 * 68);
  // acc -> LDS bf16 (+bias). Q/K: [r][c] (conflict-free); V: [c][r] (2-way, free).
#pragma unroll
  for (int mi = 0; mi < 4; ++mi) {
#pragma unroll
    for (int ni = 0; ni < 4; ++ni) {
      const int c = ni * 16 + l15;
      const float bi = bias[col0 + c];
#pragma unroll
      for (int j = 0; j < 4; ++j) {
        const int r = mi * 16 + lr4 + j;
        tw[isV ? (c * 68 + r) : (r * 68 + c)] = f2bf(acc[mi][ni][j] + bi);
      }
    }
  }
  // wave-private LDS: same-wave ds ops are ordered -> no barrier (pattern proven in k_attn).
  // Read 8 rows/pass x 8 passes; 8 lanes cover one row (2x short4v = 16B), store 16B global.
  unsigned short* outp;
  size_t rstride;
  if (isV) {        // row = d, cols = s
    outp = VTo + (((size_t)b * TH + h0) * THS) * TS + s0;
    rstride = TS;
  } else {          // row = s, cols = d
    outp = (reg == 0 ? Qo : Ko) + (((size_t)b * TH + h0) * TS + s0) * THS;
    rstride = THS;
  }
#pragma unroll
  for (int p2 = 0; p2 < 8; ++p2) {
    const int rp = p2 * 8 + (lane >> 3);
    const int co = (lane & 7) * 8;
    union { short4v h[2]; short8 s8; } u;
    u.h[0] = *(const short4v*)&tw[rp * 68 + co];
    u.h[1] = *(const short4v*)&tw[rp * 68 + co + 4];
    *(short8*)(outp + (size_t)rp * rstride + co) = u.s8;
  }
}

// ---------------- flash attention, causal, swapped-operand in-register softmax ----------------
// EXACT R2 kernel (best measured: 69.2 us). 1 block = 4 waves, each wave owns 32 q-rows,
// KVBLK=32, 32x32x16 MFMA, barrier-free independent waves, b-complement load balance.
__global__ __launch_bounds__(256) void k_attn(const unsigned short* __restrict__ Q,
                                              const unsigned short* __restrict__ K,
                                              const unsigned short* __restrict__ VT,
                                              unsigned short* __restrict__ attn) {
  __shared__ unsigned short sO[4][32 * 68];  // per-wave O transpose buffer, stride 68
  const int lane = threadIdx.x & 63, wave = threadIdx.x >> 6;
  const int l31 = lane & 31, h = lane >> 5;
  int qt = blockIdx.x;
  const int hh = blockIdx.y, b = blockIdx.z;
  if (b) qt = 15 - qt;  // complement pairing balances the causal triangle across CUs
  const int qrb = qt * 128 + wave * 32;

  const unsigned short* Qh = Q + (((size_t)b * TH + hh) * TS) * THS;
  const unsigned short* Kh = K + (((size_t)b * TH + hh) * TS) * THS;
  const unsigned short* Vh = VT + (((size_t)b * TH + hh) * THS) * TS;

  // Q B-frags: lane holds row (qrb + l31), d-chunk c*16 + h*8
  short8 qf[4];
#pragma unroll
  for (int c2 = 0; c2 < 4; ++c2)
    qf[c2] = *(const short8*)&Qh[(size_t)(qrb + l31) * THS + c2 * 16 + h * 8];

  f32x16 o0 = {}, o1 = {};
  float m_run = -1e30f, l_run = 0.f;
  const float cl2e = 0.125f * 1.44269504088896340736f;  // scale * log2(e)

  const int nkt = (qrb >> 5) + 1;

  // K A-frags for tile 0 (prefetch pattern: loaded before loop, next tile loaded mid-iteration)
  short8 kf[4];
#pragma unroll
  for (int c2 = 0; c2 < 4; ++c2)
    kf[c2] = *(const short8*)&Kh[(size_t)l31 * THS + c2 * 16 + h * 8];

  for (int kt = 0; kt < nkt; ++kt) {
    const int kb = kt * 32;
    // V^T A-frags for current tile (consumed after softmax -> latency-tolerant)
    short8 vf[2][2];
#pragma unroll
    for (int t = 0; t < 2; ++t)
#pragma unroll
      for (int c2 = 0; c2 < 2; ++c2)
        vf[t][c2] = *(const short8*)&Vh[(size_t)(t * 32 + l31) * TS + kb + c2 * 16 + h * 8];

    // S^T[k][q] accumulate over d
    f32x16 s = {};
#pragma unroll
    for (int c2 = 0; c2 < 4; ++c2)
      s = __builtin_amdgcn_mfma_f32_32x32x16_bf16(kf[c2], qf[c2], s, 0, 0, 0);

    // prefetch next K tile (in-place; WAR on kf is safe, loads issue after mfma reads)
    if (kt + 1 < nkt) {
#pragma unroll
      for (int c2 = 0; c2 < 4; ++c2)
        kf[c2] = *(const short8*)&Kh[(size_t)(kb + 32 + l31) * THS + c2 * 16 + h * 8];
    }

    // causal mask on the diagonal tile (kb == qrb): k-row (reg-mapped) <= q (lane-mapped)
    if (kt == nkt - 1) {
#pragma unroll
      for (int r = 0; r < 16; ++r)
        if ((r & 3) + 8 * (r >> 2) + 4 * h > l31) s[r] = -1e30f;
    }

    // online softmax: per-lane state for q = l31 (replicated in both halves)
    float tm = s[0];
#pragma unroll
    for (int r = 1; r < 16; ++r) tm = fmaxf(tm, s[r]);
    tm = fmaxf(tm, __shfl_xor(tm, 32));
    const float mn = fmaxf(m_run, tm);
    const float al = __builtin_amdgcn_exp2f((m_run - mn) * cl2e);
    m_run = mn;
    float ts = 0.f;
#pragma unroll
    for (int r = 0; r < 16; ++r) {
      const float p = __builtin_amdgcn_exp2f((s[r] - mn) * cl2e);
      s[r] = p;
      ts += p;
    }
    ts += __shfl_xor(ts, 32);
    l_run = l_run * al + ts;
    o0 *= al;
    o1 *= al;

    // P^T B-frags: pack pairs to bf16, pairwise permlane32_swap -> frag words in order
    unsigned B0 = cvtpk(s[0], s[1]), B1 = cvtpk(s[2], s[3]);
    unsigned B2 = cvtpk(s[4], s[5]), B3 = cvtpk(s[6], s[7]);
    swap32(B0, B2);
    swap32(B1, B3);
    unsigned B4 = cvtpk(s[8], s[9]), B5 = cvtpk(s[10], s[11]);
    unsigned B6 = cvtpk(s[12], s[13]), B7 = cvtpk(s[14], s[15]);
    swap32(B4, B6);
    swap32(B5, B7);
    union U { uint4v u; short8 s8; } u0, u1;
    u0.u = (uint4v){B0, B1, B2, B3};
    u1.u = (uint4v){B4, B5, B6, B7};

    o0 = __builtin_amdgcn_mfma_f32_32x32x16_bf16(vf[0][0], u0.s8, o0, 0, 0, 0);
    o0 = __builtin_amdgcn_mfma_f32_32x32x16_bf16(vf[0][1], u1.s8, o0, 0, 0, 0);
    o1 = __builtin_amdgcn_mfma_f32_32x32x16_bf16(vf[1][0], u0.s8, o1, 0, 0, 0);
    o1 = __builtin_amdgcn_mfma_f32_32x32x16_bf16(vf[1][1], u1.s8, o1, 0, 0, 0);
  }

  // epilogue: O^T -> LDS (wave-private, no barrier needed) -> coalesced global store
  const float inv = 1.0f / l_run;
  unsigned* so32 = (unsigned*)&sO[wave][0];
#pragma unroll
  for (int j2 = 0; j2 < 8; ++j2) {
    const int d0 = ((2 * j2) & 3) + 8 * (j2 >> 1) + 4 * h;  // even d of the pair
    so32[l31 * 34 + (d0 >> 1)] = cvtpk(o0[2 * j2] * inv, o0[2 * j2 + 1] * inv);
    so32[l31 * 34 + ((32 + d0) >> 1)] = cvtpk(o1[2 * j2] * inv, o1[2 * j2 + 1] * inv);
  }
#pragma unroll
  for (int p2 = 0; p2 < 4; ++p2) {
    const int rp = p2 * 8 + (lane >> 3);
    const int co = (lane & 7) * 8;
    short4v va = *(const short4v*)&sO[wave][rp * 68 + co];
    short4v vb = *(const short4v*)&sO[wave][rp * 68 + co + 4];
    unsigned short* gp = &attn[(size_t)(b * TS + qrb + rp) * TD + hh * THS + co];
    *(short4v*)gp = va;
    *(short4v*)(gp + 4) = vb;
  }
}

// ---------------- GEMM2: out = attn @ wpT^T + bias (fp32 out) ----------------
__global__ __launch_bounds__(256) void k_gemm_proj(const unsigned short* __restrict__ A,
                                                   const unsigned short* __restrict__ BT,
                                                   const float* __restrict__ bias,
                                                   float* __restrict__ out) {
  __shared__ unsigned short sA[2 * 4096];
  __shared__ unsigned short sB[2 * 4096];
  f32x4 acc[4][4];
  const int m0 = blockIdx.y * 128, n0 = blockIdx.x * 128;
  gemm_core_k1024(A, BT, m0, n0, sA, sB, acc);

  const int lane = threadIdx.x & 63, wave = threadIdx.x >> 6;
  const int wm = wave >> 1, wn = wave & 1;
  const int lr4 = (lane >> 4) * 4, l15 = lane & 15;
#pragma unroll
  for (int mi = 0; mi < 4; ++mi) {
    const int row = m0 + wm * 64 + mi * 16 + lr4;
#pragma unroll
    for (int ni = 0; ni < 4; ++ni) {
      const int col = n0 + wn * 64 + ni * 16 + l15;
      const float bi = bias[col];
#pragma unroll
      for (int j = 0; j < 4; ++j)
        out[(size_t)(row + j) * TD + col] = acc[mi][ni][j] + bi;
    }
  }
}

extern "C" void kernel_launch(void* const* d_in, const int* in_sizes, int n_in,
                              void* d_out, int out_size, void* d_ws, size_t ws_size,
                              hipStream_t stream) {
  const float* x = (const float*)d_in[0];
  const float* c_attn_w = (const float*)d_in[1];
  const float* c_attn_b = (const float*)d_in[2];
  const float* c_proj_w = (const float*)d_in[3];
  const float* c_proj_b = (const float*)d_in[4];
  float* out = (float*)d_out;

  const size_t SZ_XB = (size_t)4096 * 1024 * 2;
  const size_t SZ_WAT = (size_t)3072 * 1024 * 2;
  const size_t SZ_WPT = (size_t)1024 * 1024 * 2;
  const size_t SZ_HEAD = (size_t)TB * TH * TS * THS * 2;
  const size_t SZ_ATT = (size_t)4096 * 1024 * 2;
  if (ws_size < SZ_XB + SZ_WAT + SZ_WPT + 3 * SZ_HEAD + SZ_ATT) return;

  char* ws = (char*)d_ws;
  unsigned short* xb = (unsigned short*)ws;   ws += SZ_XB;
  unsigned short* waT = (unsigned short*)ws;  ws += SZ_WAT;
  unsigned short* wpT = (unsigned short*)ws;  ws += SZ_WPT;
  unsigned short* Qb = (unsigned short*)ws;   ws += SZ_HEAD;
  unsigned short* Kb = (unsigned short*)ws;   ws += SZ_HEAD;
  unsigned short* VTb = (unsigned short*)ws;  ws += SZ_HEAD;
  unsigned short* attn = (unsigned short*)ws; ws += SZ_ATT;

  k_cvt_bf16x4<<<4096, 256, 0, stream>>>(x, (ushort4*)xb, 4096 * 1024 / 4);
  k_transpose_bf<<<dim3(3072 / 32, 1024 / 32), 256, 0, stream>>>(c_attn_w, waT, 1024, 3072);
  k_transpose_bf<<<dim3(1024 / 32, 1024 / 32), 256, 0, stream>>>(c_proj_w, wpT, 1024, 1024);
  k_gemm_qkv<<<dim3(3072 / 128, 4096 / 128), 256, 0, stream>>>(xb, waT, c_attn_b, Qb, Kb, VTb);
  k_attn<<<dim3(16, TH, TB), 256, 0, stream>>>(Qb, Kb, VTb, attn);
  k_gemm_proj<<<dim3(1024 / 128, 4096 / 128), 256, 0, stream>>>(attn, wpT, c_proj_b, out);
}